// Round 1
// baseline (942.867 us; speedup 1.0000x reference)
//
#include <hip/hip_runtime.h>
#include <cstdint>
#include <cstddef>

#define B_ 2
#define N_ 384
#define D_ 128
#define NN (N_*N_)                  // 147456
#define BN (B_*N_)                  // 768
#define EDGE_ELEMS (B_*NN*D_)       // 37748736
#define NODE_ELEMS (BN*D_)          // 98304

typedef short bh8 __attribute__((ext_vector_type(8)));
typedef float f32x4 __attribute__((ext_vector_type(4)));

__device__ __forceinline__ f32x4 mfma_bf16(bh8 a, bh8 b, f32x4 c){
  return __builtin_amdgcn_mfma_f32_16x16x32_bf16(a, b, c, 0, 0, 0);
}
__device__ __forceinline__ unsigned short f2bf(float f){
  unsigned u = __float_as_uint(f);
  return (unsigned short)((u + 0x7fffu + ((u >> 16) & 1u)) >> 16);
}
__device__ __forceinline__ float geluf(float x){
  return 0.5f * x * (1.0f + erff(x * 0.70710678118654752f));
}
__device__ __forceinline__ f32x4 zero4(){ f32x4 z = {0.f,0.f,0.f,0.f}; return z; }

// ---------------- prep: bf16-transpose the 5 MFMA weights ----------------
__global__ void kprep_w(const float* wqkv_e, const float* e0_we, const float* e0_w1,
                        const float* e1_w1, const float* e1_w2,
                        unsigned short* WqkvT, unsigned short* WeT, unsigned short* W1T,
                        unsigned short* E1W1T, unsigned short* E1W2T){
  int m = blockIdx.y;
  const float* src; unsigned short* dst; int K, Nn;
  if (m == 0){ src = wqkv_e; dst = WqkvT; K = 128; Nn = 512; }
  else if (m == 1){ src = e0_we; dst = WeT;   K = 256; Nn = 128; }
  else if (m == 2){ src = e0_w1; dst = W1T;   K = 128; Nn = 128; }
  else if (m == 3){ src = e1_w1; dst = E1W1T; K = 128; Nn = 256; }
  else            { src = e1_w2; dst = E1W2T; K = 256; Nn = 128; }
  int idx = blockIdx.x * 256 + threadIdx.x;
  if (idx < K * Nn){
    int n = idx / K, k = idx % K;
    dst[idx] = f2bf(src[k * Nn + n]);   // dst[n][k] = src[k][n]
  }
}

// ---------------- prep: edge fp32 -> bf16 ----------------
__global__ void kprep_e(const float* __restrict__ edge, unsigned short* __restrict__ E16){
  int idx = blockIdx.x * 256 + threadIdx.x;   // float4 index
  if (idx < EDGE_ELEMS / 4){
    float4 v = ((const float4*)edge)[idx];
    ushort4 o;
    o.x = f2bf(v.x); o.y = f2bf(v.y); o.z = f2bf(v.z); o.w = f2bf(v.w);
    ((ushort4*)E16)[idx] = o;
  }
}

// ---------------- prep: means over axis1 (i) and axis2 (j) ----------------
__global__ void kmeans(const float* __restrict__ edge, float* __restrict__ meanJ,
                       float* __restrict__ meanI){
  int blk = blockIdx.x;
  int d = threadIdx.x;
  if (blk < BN){                       // meanJ[b,i,d] = mean_j edge[b,i,j,d]
    const float* p = edge + (size_t)blk * N_ * D_ + d;
    float s = 0.f;
    #pragma unroll 8
    for (int j = 0; j < N_; ++j) s += p[(size_t)j * D_];
    meanJ[blk * D_ + d] = s * (1.0f / N_);
  } else {                             // meanI[b,j,d] = mean_i edge[b,i,j,d]
    int blk2 = blk - BN;
    int b = blk2 / N_, j = blk2 % N_;
    const float* p = edge + ((size_t)b * NN + j) * D_ + d;
    float s = 0.f;
    #pragma unroll 8
    for (int i = 0; i < N_; ++i) s += p[(size_t)i * N_ * D_];
    meanI[blk2 * D_ + d] = s * (1.0f / N_);
  }
}

// ---------------- node qkv: qkvn[b,i,:] = node row @ wqkv_n (fp32) ----------------
__global__ void kqkvn(const float* __restrict__ node, const float* __restrict__ wqkv_n,
                      float* __restrict__ qkvn){
  int row = blockIdx.x;       // b*N+i
  int c = threadIdx.x;        // 0..383
  __shared__ float sn[128];
  if (c < 128) sn[c] = node[row * 128 + c];
  __syncthreads();
  float acc = 0.f;
  #pragma unroll 8
  for (int k = 0; k < 128; ++k) acc += sn[k] * wqkv_n[k * 384 + c];
  qkvn[row * 384 + c] = acc;
}

// ---------------- fused attention: qkv_e GEMM on the fly + online softmax ------------
// grid = BN blocks, 256 thr (4 waves). wave w handles heads 2w,2w+1 sequentially.
__global__ __launch_bounds__(256, 2) void kattn(const unsigned short* __restrict__ E16,
                      const unsigned short* __restrict__ WqkvT,
                      const float* __restrict__ qkvn, float* __restrict__ attn){
  int bi = blockIdx.x; int b = bi / N_, i = bi % N_;
  int tid = threadIdx.x;
  int w = tid >> 6, lane = tid & 63, quad = lane >> 4, c16 = lane & 15;
  const float scale = 0.08838834764831845f;   // 1/sqrt(128)
  const unsigned short* Abase = E16 + (size_t)bi * N_ * D_;
  for (int s = 0; s < 2; ++s){
    int h = w * 2 + s;
    bh8 bf[4][4];     // tiles u: 0=eq 1=ek 2=ev 3=em, 4 K-steps
    #pragma unroll
    for (int u = 0; u < 4; ++u)
      #pragma unroll
      for (int ks = 0; ks < 4; ++ks){
        int col = w * 128 + s * 64 + u * 16 + c16;
        bf[u][ks] = *(const bh8*)(WqkvT + col * 128 + ks * 32 + quad * 8);
      }
    float qv = qkvn[(b * N_ + i) * 384 + h * 48 + c16];
    float m_run = -1e30f, l_run = 0.f, o = 0.f;
    for (int jt = 0; jt < 24; ++jt){
      bh8 af[4];
      #pragma unroll
      for (int ks = 0; ks < 4; ++ks)
        af[ks] = *(const bh8*)(Abase + (size_t)(jt * 16 + c16) * D_ + ks * 32 + quad * 8);
      f32x4 EQ = zero4(), EK = zero4(), EV = zero4(), EM = zero4();
      #pragma unroll
      for (int ks = 0; ks < 4; ++ks){
        EQ = mfma_bf16(af[ks], bf[0][ks], EQ);
        EK = mfma_bf16(af[ks], bf[1][ks], EK);
        EV = mfma_bf16(af[ks], bf[2][ks], EV);
        EM = mfma_bf16(af[ks], bf[3][ks], EM);
      }
      // rows j = jt*16 + quad*4 + r ; cols d = c16
      const float* kvb = qkvn + ((size_t)b * N_ + jt * 16 + quad * 4) * 384 + h * 48;
      float dots[4], vv[4];
      #pragma unroll
      for (int r = 0; r < 4; ++r){
        float knv = kvb[r * 384 + 16 + c16];
        float vnv = kvb[r * 384 + 32 + c16];
        float t1 = (qv + EQ[r]) * (knv + EK[r]);
        t1 += __shfl_xor(t1, 1); t1 += __shfl_xor(t1, 2);
        t1 += __shfl_xor(t1, 4); t1 += __shfl_xor(t1, 8);
        dots[r] = t1 * scale;
        vv[r] = vnv * EM[r] + EV[r];
      }
      float tmax = fmaxf(fmaxf(dots[0], dots[1]), fmaxf(dots[2], dots[3]));
      tmax = fmaxf(tmax, __shfl_xor(tmax, 16));
      tmax = fmaxf(tmax, __shfl_xor(tmax, 32));
      float mnew = fmaxf(m_run, tmax);
      float al = __expf(m_run - mnew);
      float p0 = __expf(dots[0] - mnew), p1 = __expf(dots[1] - mnew);
      float p2 = __expf(dots[2] - mnew), p3 = __expf(dots[3] - mnew);
      float lt = p0 + p1 + p2 + p3;
      lt += __shfl_xor(lt, 16); lt += __shfl_xor(lt, 32);
      l_run = l_run * al + lt;
      m_run = mnew;
      o = o * al + p0 * vv[0] + p1 * vv[1] + p2 * vv[2] + p3 * vv[3];
    }
    o += __shfl_xor(o, 16); o += __shfl_xor(o, 32);
    o /= l_run;
    if (quad == 0) attn[(size_t)bi * D_ + h * 16 + c16] = o;
  }
}

// ---------------- node updates: lin0 + LN0 + MLP + LN1 (fp32) ----------------
__global__ void knode(const float* __restrict__ node, const float* __restrict__ attn,
                      const float* lin0_w, const float* lin0_b,
                      const float* g0, const float* bb0,
                      const float* w1, const float* w2, const float* b2,
                      const float* g1, const float* bb1,
                      float* __restrict__ xOut){
  int row = blockIdx.x; int tid = threadIdx.x;
  __shared__ float sa[128], sx[128], sh[256], rb[8];
  if (tid < 128) sa[tid] = attn[row * 128 + tid];
  __syncthreads();
  float y = 0.f, x0 = 0.f;
  if (tid < 128){
    float acc = lin0_b[tid];
    #pragma unroll 8
    for (int k = 0; k < 128; ++k) acc += sa[k] * lin0_w[k * 128 + tid];
    y = acc + node[row * 128 + tid];
  }
  { float sv = (tid < 128) ? y : 0.f, sq = (tid < 128) ? y * y : 0.f;
    #pragma unroll
    for (int m2 = 32; m2 >= 1; m2 >>= 1){ sv += __shfl_xor(sv, m2); sq += __shfl_xor(sq, m2); }
    if ((tid & 63) == 0){ rb[tid >> 6] = sv; rb[4 + (tid >> 6)] = sq; } }
  __syncthreads();
  float mean = (rb[0] + rb[1] + rb[2] + rb[3]) * (1.f / 128.f);
  float var  = (rb[4] + rb[5] + rb[6] + rb[7]) * (1.f / 128.f) - mean * mean;
  float rstd = rsqrtf(var + 1e-5f);
  if (tid < 128){ x0 = (y - mean) * rstd * g0[tid] + bb0[tid]; sx[tid] = x0; }
  __syncthreads();
  { float acc = 0.f;
    #pragma unroll 8
    for (int k = 0; k < 128; ++k) acc += sx[k] * w1[k * 256 + tid];
    sh[tid] = geluf(acc); }
  __syncthreads();
  float y2 = 0.f;
  if (tid < 128){
    float acc = b2[tid];
    #pragma unroll 8
    for (int e = 0; e < 256; ++e) acc += sh[e] * w2[e * 128 + tid];
    y2 = acc + x0;
  }
  __syncthreads();
  { float sv = (tid < 128) ? y2 : 0.f, sq = (tid < 128) ? y2 * y2 : 0.f;
    #pragma unroll
    for (int m2 = 32; m2 >= 1; m2 >>= 1){ sv += __shfl_xor(sv, m2); sq += __shfl_xor(sq, m2); }
    if ((tid & 63) == 0){ rb[tid >> 6] = sv; rb[4 + (tid >> 6)] = sq; } }
  __syncthreads();
  mean = (rb[0] + rb[1] + rb[2] + rb[3]) * (1.f / 128.f);
  var  = (rb[4] + rb[5] + rb[6] + rb[7]) * (1.f / 128.f) - mean * mean;
  rstd = rsqrtf(var + 1e-5f);
  if (tid < 128) xOut[row * 128 + tid] = (y2 - mean) * rstd * g1[tid] + bb1[tid];
}

// -------- per-row addends: rowAdd = sn+te+be (by i), colAdd = tn+se (by j) --------
__global__ void kaddends(const float* __restrict__ xOut, const float* __restrict__ meanJ,
                         const float* __restrict__ meanI,
                         const float* ws, const float* bs, const float* wt, const float* bt,
                         const float* wer, const float* wec, const float* be,
                         float* __restrict__ rowAdd, float* __restrict__ colAdd){
  int row = blockIdx.x; int d = threadIdx.x;
  __shared__ float sx[128], smJ[128], smI[128];
  sx[d] = xOut[row * 128 + d]; smJ[d] = meanJ[row * 128 + d]; smI[d] = meanI[row * 128 + d];
  __syncthreads();
  float s1 = bs[d], s2 = bt[d], s3 = 0.f, s4 = 0.f;
  #pragma unroll 8
  for (int k = 0; k < 128; ++k){
    s1 += sx[k]  * ws[k * 128 + d];
    s2 += sx[k]  * wt[k * 128 + d];
    s3 += smJ[k] * wer[k * 128 + d];
    s4 += smI[k] * wec[k * 128 + d];
  }
  rowAdd[row * 128 + d] = s1 + s3 + be[d];
  colAdd[row * 128 + d] = s2 + s4;
}

// ---------------- fused edge pipeline: 4 chained MFMA GEMMs + 2 LN, 64-row tiles ----
__global__ __launch_bounds__(256, 2) void kedge(
    const unsigned short* __restrict__ E16, const unsigned short* __restrict__ WeT,
    const unsigned short* __restrict__ W1T, const unsigned short* __restrict__ E1W1T,
    const unsigned short* __restrict__ E1W2T,
    const float* __restrict__ rowAdd, const float* __restrict__ colAdd,
    const float* __restrict__ edge,
    const float* b1, const float* eg0, const float* eb0,
    const float* e1b2, const float* eg1, const float* eb1,
    float* __restrict__ eOut){
  __shared__ unsigned short lA[64 * 264];    // 256-wide bf16 tile, padded (+8)
  __shared__ unsigned short lB[64 * 136];    // 128-wide bf16 tile, padded (+8)
  __shared__ float lrS[4][64], lrQ[4][64];
  int tid = threadIdx.x;
  int w = tid >> 6, lane = tid & 63, quad = lane >> 4, c16 = lane & 15;
  int R0 = blockIdx.x * 64;
  int b = R0 / NN; int rem = R0 % NN; int i = rem / N_; int j0 = rem % N_;

  // ---- stage A1 = [edge(b,i,j0+m,:) | edge(b,j0+m,i,:)] as bf16, 64x256 ----
  {
    const unsigned short* rowBaseA = E16 + ((size_t)(b * N_ + i) * N_ + j0) * D_;
    #pragma unroll
    for (int it = 0; it < 8; ++it){
      int cid = it * 256 + tid;
      int rrow = cid >> 5;
      int kc = (cid & 31) * 8;
      const unsigned short* src;
      if (kc < 128) src = rowBaseA + (size_t)rrow * D_ + kc;
      else          src = E16 + ((size_t)(b * N_ + j0 + rrow) * N_ + i) * D_ + (kc - 128);
      *(float4*)(lA + rrow * 264 + kc) = *(const float4*)src;
    }
  }
  __syncthreads();

  // ---- G1: C1 = A1 @ WeT^T (K=256, N=128), col-split: wave w -> cols [32w,32w+32) ----
  f32x4 acc1[2][4];
  #pragma unroll
  for (int t = 0; t < 2; ++t) for (int ms = 0; ms < 4; ++ms) acc1[t][ms] = zero4();
  for (int ks = 0; ks < 8; ++ks){
    bh8 af[4];
    #pragma unroll
    for (int ms = 0; ms < 4; ++ms)
      af[ms] = *(const bh8*)(lA + (ms * 16 + c16) * 264 + ks * 32 + quad * 8);
    bh8 bfr[2];
    #pragma unroll
    for (int t = 0; t < 2; ++t){
      int col = w * 32 + t * 16 + c16;
      bfr[t] = *(const bh8*)(WeT + col * 256 + ks * 32 + quad * 8);
    }
    #pragma unroll
    for (int t = 0; t < 2; ++t)
      #pragma unroll
      for (int ms = 0; ms < 4; ++ms)
        acc1[t][ms] = mfma_bf16(af[ms], bfr[t], acc1[t][ms]);
  }
  // epilogue G1: + rowAdd(i) + colAdd(j) -> gelu -> lB (bf16)
  {
    float rA[2];
    #pragma unroll
    for (int t = 0; t < 2; ++t) rA[t] = rowAdd[(b * N_ + i) * D_ + w * 32 + t * 16 + c16];
    #pragma unroll
    for (int ms = 0; ms < 4; ++ms)
      #pragma unroll
      for (int r = 0; r < 4; ++r){
        int m = ms * 16 + quad * 4 + r;
        const float* cA = colAdd + (size_t)(b * N_ + j0 + m) * D_;
        #pragma unroll
        for (int t = 0; t < 2; ++t){
          int c = w * 32 + t * 16 + c16;
          float v = acc1[t][ms][r] + rA[t] + cA[c];
          lB[m * 136 + c] = f2bf(geluf(v));
        }
      }
  }
  __syncthreads();

  // ---- G2: C2 = gelu-tile @ W1T^T (K=128, N=128) + b1 + edge -> LN -> edge2 ----
  f32x4 acc2[2][4];
  #pragma unroll
  for (int t = 0; t < 2; ++t) for (int ms = 0; ms < 4; ++ms) acc2[t][ms] = zero4();
  for (int ks = 0; ks < 4; ++ks){
    bh8 af[4];
    #pragma unroll
    for (int ms = 0; ms < 4; ++ms)
      af[ms] = *(const bh8*)(lB + (ms * 16 + c16) * 136 + ks * 32 + quad * 8);
    bh8 bfr[2];
    #pragma unroll
    for (int t = 0; t < 2; ++t){
      int col = w * 32 + t * 16 + c16;
      bfr[t] = *(const bh8*)(W1T + col * 128 + ks * 32 + quad * 8);
    }
    #pragma unroll
    for (int t = 0; t < 2; ++t)
      #pragma unroll
      for (int ms = 0; ms < 4; ++ms)
        acc2[t][ms] = mfma_bf16(af[ms], bfr[t], acc2[t][ms]);
  }
  float b1v[2], g0v[2], b0v[2];
  #pragma unroll
  for (int t = 0; t < 2; ++t){
    int c = w * 32 + t * 16 + c16;
    b1v[t] = b1[c]; g0v[t] = eg0[c]; b0v[t] = eb0[c];
  }
  const float* edgeBase = edge + ((size_t)(b * N_ + i) * N_ + j0) * D_;
  #pragma unroll
  for (int ms = 0; ms < 4; ++ms)
    #pragma unroll
    for (int r = 0; r < 4; ++r){
      int m = ms * 16 + quad * 4 + r;
      float s = 0.f, q = 0.f;
      #pragma unroll
      for (int t = 0; t < 2; ++t){
        int c = w * 32 + t * 16 + c16;
        float v = acc2[t][ms][r] + b1v[t] + edgeBase[(size_t)m * D_ + c];
        acc2[t][ms][r] = v;
        s += v; q += v * v;
      }
      s += __shfl_xor(s, 1); s += __shfl_xor(s, 2); s += __shfl_xor(s, 4); s += __shfl_xor(s, 8);
      q += __shfl_xor(q, 1); q += __shfl_xor(q, 2); q += __shfl_xor(q, 4); q += __shfl_xor(q, 8);
      if (c16 == 0){ lrS[w][m] = s; lrQ[w][m] = q; }
    }
  __syncthreads();
  #pragma unroll
  for (int ms = 0; ms < 4; ++ms)
    #pragma unroll
    for (int r = 0; r < 4; ++r){
      int m = ms * 16 + quad * 4 + r;
      float s = lrS[0][m] + lrS[1][m] + lrS[2][m] + lrS[3][m];
      float q = lrQ[0][m] + lrQ[1][m] + lrQ[2][m] + lrQ[3][m];
      float mean = s * (1.f / 128.f);
      float var  = q * (1.f / 128.f) - mean * mean;
      float rstd = rsqrtf(var + 1e-5f);
      #pragma unroll
      for (int t = 0; t < 2; ++t){
        int c = w * 32 + t * 16 + c16;
        float v = (acc2[t][ms][r] - mean) * rstd * g0v[t] + b0v[t];
        acc2[t][ms][r] = v;                 // retain edge2 fp32 for G4 residual
        lB[m * 136 + c] = f2bf(v);          // edge2 bf16 -> A operand of G3
      }
    }
  __syncthreads();

  // ---- G3: C3 = edge2 @ E1W1T^T (K=128, N=256), col-split: wave w -> cols [64w,64w+64) ----
  f32x4 acc3[4][4];
  #pragma unroll
  for (int t = 0; t < 4; ++t) for (int ms = 0; ms < 4; ++ms) acc3[t][ms] = zero4();
  for (int ks = 0; ks < 4; ++ks){
    bh8 af[4];
    #pragma unroll
    for (int ms = 0; ms < 4; ++ms)
      af[ms] = *(const bh8*)(lB + (ms * 16 + c16) * 136 + ks * 32 + quad * 8);
    bh8 bfr[4];
    #pragma unroll
    for (int t = 0; t < 4; ++t){
      int col = w * 64 + t * 16 + c16;
      bfr[t] = *(const bh8*)(E1W1T + col * 128 + ks * 32 + quad * 8);
    }
    #pragma unroll
    for (int t = 0; t < 4; ++t)
      #pragma unroll
      for (int ms = 0; ms < 4; ++ms)
        acc3[t][ms] = mfma_bf16(af[ms], bfr[t], acc3[t][ms]);
  }
  #pragma unroll
  for (int t = 0; t < 4; ++t)
    #pragma unroll
    for (int ms = 0; ms < 4; ++ms)
      #pragma unroll
      for (int r = 0; r < 4; ++r){
        int m = ms * 16 + quad * 4 + r;
        int cc = w * 64 + t * 16 + c16;
        lA[m * 264 + cc] = f2bf(geluf(acc3[t][ms][r]));
      }
  __syncthreads();

  // ---- G4: C4 = gelu-tile @ E1W2T^T (K=256, N=128) + b2 + edge2 -> LN -> out ----
  f32x4 acc4[2][4];
  #pragma unroll
  for (int t = 0; t < 2; ++t) for (int ms = 0; ms < 4; ++ms) acc4[t][ms] = zero4();
  for (int ks = 0; ks < 8; ++ks){
    bh8 af[4];
    #pragma unroll
    for (int ms = 0; ms < 4; ++ms)
      af[ms] = *(const bh8*)(lA + (ms * 16 + c16) * 264 + ks * 32 + quad * 8);
    bh8 bfr[2];
    #pragma unroll
    for (int t = 0; t < 2; ++t){
      int col = w * 32 + t * 16 + c16;
      bfr[t] = *(const bh8*)(E1W2T + col * 256 + ks * 32 + quad * 8);
    }
    #pragma unroll
    for (int t = 0; t < 2; ++t)
      #pragma unroll
      for (int ms = 0; ms < 4; ++ms)
        acc4[t][ms] = mfma_bf16(af[ms], bfr[t], acc4[t][ms]);
  }
  float b2v[2], g1v[2], bb1v[2];
  #pragma unroll
  for (int t = 0; t < 2; ++t){
    int c = w * 32 + t * 16 + c16;
    b2v[t] = e1b2[c]; g1v[t] = eg1[c]; bb1v[t] = eb1[c];
  }
  #pragma unroll
  for (int ms = 0; ms < 4; ++ms)
    #pragma unroll
    for (int r = 0; r < 4; ++r){
      int m = ms * 16 + quad * 4 + r;
      float s = 0.f, q = 0.f;
      #pragma unroll
      for (int t = 0; t < 2; ++t){
        float v = acc4[t][ms][r] + b2v[t] + acc2[t][ms][r];
        acc4[t][ms][r] = v;
        s += v; q += v * v;
      }
      s += __shfl_xor(s, 1); s += __shfl_xor(s, 2); s += __shfl_xor(s, 4); s += __shfl_xor(s, 8);
      q += __shfl_xor(q, 1); q += __shfl_xor(q, 2); q += __shfl_xor(q, 4); q += __shfl_xor(q, 8);
      if (c16 == 0){ lrS[w][m] = s; lrQ[w][m] = q; }
    }
  __syncthreads();
  float* outBase = eOut + ((size_t)(b * N_ + i) * N_ + j0) * D_;
  #pragma unroll
  for (int ms = 0; ms < 4; ++ms)
    #pragma unroll
    for (int r = 0; r < 4; ++r){
      int m = ms * 16 + quad * 4 + r;
      float s = lrS[0][m] + lrS[1][m] + lrS[2][m] + lrS[3][m];
      float q = lrQ[0][m] + lrQ[1][m] + lrQ[2][m] + lrQ[3][m];
      float mean = s * (1.f / 128.f);
      float var  = q * (1.f / 128.f) - mean * mean;
      float rstd = rsqrtf(var + 1e-5f);
      #pragma unroll
      for (int t = 0; t < 2; ++t){
        int c = w * 32 + t * 16 + c16;
        outBase[(size_t)m * D_ + c] = (acc4[t][ms][r] - mean) * rstd * g1v[t] + bb1v[t];
      }
    }
}

extern "C" void kernel_launch(void* const* d_in, const int* in_sizes, int n_in,
                              void* d_out, int out_size, void* d_ws, size_t ws_size,
                              hipStream_t stream){
  const float* node   = (const float*)d_in[0];
  const float* edge   = (const float*)d_in[1];
  const float* wqkv_n = (const float*)d_in[3];
  const float* wqkv_e = (const float*)d_in[4];
  const float* lin0_w = (const float*)d_in[5];
  const float* lin0_b = (const float*)d_in[6];
  const float* ln0_g  = (const float*)d_in[7];
  const float* ln0_b  = (const float*)d_in[8];
  const float* ln1_g  = (const float*)d_in[9];
  const float* ln1_b  = (const float*)d_in[10];
  const float* nmlp_w1= (const float*)d_in[11];
  const float* nmlp_w2= (const float*)d_in[12];
  const float* nmlp_b2= (const float*)d_in[13];
  const float* e0_we  = (const float*)d_in[14];
  const float* e0_be  = (const float*)d_in[15];
  const float* e0_ws  = (const float*)d_in[16];
  const float* e0_bs  = (const float*)d_in[17];
  const float* e0_wt  = (const float*)d_in[18];
  const float* e0_bt  = (const float*)d_in[19];
  const float* e0_wer = (const float*)d_in[20];
  const float* e0_wec = (const float*)d_in[21];
  const float* e0_w1  = (const float*)d_in[22];
  const float* e0_b1  = (const float*)d_in[23];
  const float* e1_w1  = (const float*)d_in[24];
  const float* e1_w2  = (const float*)d_in[25];
  const float* e1_b2  = (const float*)d_in[26];
  const float* eln0_g = (const float*)d_in[27];
  const float* eln0_b = (const float*)d_in[28];
  const float* eln1_g = (const float*)d_in[29];
  const float* eln1_b = (const float*)d_in[30];

  unsigned short* E16   = (unsigned short*)d_ws;
  unsigned short* WqkvT = E16 + (size_t)EDGE_ELEMS;
  unsigned short* WeT   = WqkvT + 65536;
  unsigned short* W1T   = WeT + 32768;
  unsigned short* E1W1T = W1T + 16384;
  unsigned short* E1W2T = E1W1T + 32768;
  float* fbase  = (float*)(E1W2T + 32768);
  float* qkvn   = fbase;
  float* attn   = qkvn + (size_t)BN * 384;
  float* meanJ  = attn + NODE_ELEMS;
  float* meanI  = meanJ + NODE_ELEMS;
  float* rowAdd = meanI + NODE_ELEMS;
  float* colAdd = rowAdd + NODE_ELEMS;

  float* xOut = (float*)d_out;
  float* eOut = xOut + NODE_ELEMS;

  kprep_w<<<dim3(256, 5), 256, 0, stream>>>(wqkv_e, e0_we, e0_w1, e1_w1, e1_w2,
                                            WqkvT, WeT, W1T, E1W1T, E1W2T);
  kprep_e<<<EDGE_ELEMS / 4 / 256, 256, 0, stream>>>(edge, E16);
  kmeans<<<2 * BN, 128, 0, stream>>>(edge, meanJ, meanI);
  kqkvn<<<BN, 384, 0, stream>>>(node, wqkv_n, qkvn);
  kattn<<<BN, 256, 0, stream>>>(E16, WqkvT, qkvn, attn);
  knode<<<BN, 256, 0, stream>>>(node, attn, lin0_w, lin0_b, ln0_g, ln0_b,
                                nmlp_w1, nmlp_w2, nmlp_b2, ln1_g, ln1_b, xOut);
  kaddends<<<BN, 128, 0, stream>>>(xOut, meanJ, meanI, e0_ws, e0_bs, e0_wt, e0_bt,
                                   e0_wer, e0_wec, e0_be, rowAdd, colAdd);
  kedge<<<EDGE_ELEMS / (64 * D_), 256, 0, stream>>>(E16, WeT, W1T, E1W1T, E1W2T,
                                                    rowAdd, colAdd, edge, e0_b1,
                                                    eln0_g, eln0_b, e1_b2, eln1_g, eln1_b,
                                                    eOut);
}